// Round 1
// baseline (329.969 us; speedup 1.0000x reference)
//
#include <hip/hip_runtime.h>
#include <hip/hip_bf16.h>
#include <cstdint>
#include <cstddef>

#define NB 8
#define TT 1024
#define DD 512
#define HH 8
#define DHD 64

using bf16x8 = __attribute__((ext_vector_type(8))) short;
using f32x4  = __attribute__((ext_vector_type(4))) float;
using s16x4  = __attribute__((ext_vector_type(4))) short;

#define MFMA(a, b, c) __builtin_amdgcn_mfma_f32_16x16x32_bf16((a), (b), (c), 0, 0, 0)

__device__ __forceinline__ short f2bf(float f) {
  union { float f; uint32_t u; } x; x.f = f;
  uint32_t r = x.u + 0x7fffu + ((x.u >> 16) & 1u);
  return (short)(r >> 16);
}

// ---------------- weight transpose + f32->bf16 ----------------
__global__ __launch_bounds__(256) void kt_transpose(
    const float* __restrict__ W0, const float* __restrict__ W1,
    const float* __restrict__ W2, const float* __restrict__ W3,
    short* __restrict__ WT)
{
  __shared__ float tile[32][33];
  int z = blockIdx.z;
  const float* W = (z == 0) ? W0 : (z == 1) ? W1 : (z == 2) ? W2 : W3;
  short* out = WT + (size_t)z * DD * DD;
  int tx = threadIdx.x, ty = threadIdx.y;  // (32, 8)
  int bx = blockIdx.x * 32, by = blockIdx.y * 32;
#pragma unroll
  for (int kq = 0; kq < 4; ++kq)
    tile[ty + kq * 8][tx] = W[(size_t)(by + ty + kq * 8) * DD + bx + tx];
  __syncthreads();
#pragma unroll
  for (int kq = 0; kq < 4; ++kq)
    out[(size_t)(bx + ty + kq * 8) * DD + by + tx] = f2bf(tile[tx][ty + kq * 8]);
}

// ---------------- QKV projection GEMM ----------------
// z: 0=Q (scaled by 1/8, layout [N,H,T,64]), 1=K ([N,H,T,64]), 2=V ([N,H,64,T])
__global__ __launch_bounds__(256) void kt_proj(
    const float* __restrict__ Xq, const float* __restrict__ Xk, const float* __restrict__ Xv,
    const short* __restrict__ WTall,
    const float* __restrict__ bq, const float* __restrict__ bk, const float* __restrict__ bv,
    short* __restrict__ qb, short* __restrict__ kb, short* __restrict__ vT)
{
  int z = blockIdx.z;
  const float* X    = (z == 0) ? Xq : (z == 1) ? Xk : Xv;
  const short* WT   = WTall + (size_t)z * DD * DD;
  const float* bias = (z == 0) ? bq : (z == 1) ? bk : bv;
  short* out        = (z == 0) ? qb : (z == 1) ? kb : vT;

  __shared__ alignas(16) short As[64][40];
  __shared__ alignas(16) short Bs[64][40];
  int tid = threadIdx.x;
  int w = tid >> 6, lane = tid & 63, g = lane >> 4, c16 = lane & 15;
  int m0 = blockIdx.x * 64, c0 = blockIdx.y * 64;
  int srow = tid >> 2, skg = (tid & 3) * 8;
  f32x4 acc[4] = {};

  for (int kk = 0; kk < DD; kk += 32) {
    const float* ap = X + (size_t)(m0 + srow) * DD + kk + skg;
    float4 a0 = *(const float4*)ap;
    float4 a1 = *(const float4*)(ap + 4);
    bf16x8 av;
    av[0] = f2bf(a0.x); av[1] = f2bf(a0.y); av[2] = f2bf(a0.z); av[3] = f2bf(a0.w);
    av[4] = f2bf(a1.x); av[5] = f2bf(a1.y); av[6] = f2bf(a1.z); av[7] = f2bf(a1.w);
    *(bf16x8*)&As[srow][skg] = av;
    *(bf16x8*)&Bs[srow][skg] = *(const bf16x8*)(WT + (size_t)(c0 + srow) * DD + kk + skg);
    __syncthreads();
    bf16x8 af = *(const bf16x8*)&As[w * 16 + c16][g * 8];
#pragma unroll
    for (int ct = 0; ct < 4; ++ct) {
      bf16x8 bfv = *(const bf16x8*)&Bs[ct * 16 + c16][g * 8];
      acc[ct] = MFMA(af, bfv, acc[ct]);
    }
    __syncthreads();
  }

#pragma unroll
  for (int ct = 0; ct < 4; ++ct) {
    int c = c0 + ct * 16 + c16;
    float bv_ = bias[c];
    int hh = c >> 6, dh = c & 63;
#pragma unroll
    for (int r = 0; r < 4; ++r) {
      int m = m0 + w * 16 + g * 4 + r;
      int n = m >> 10, t = m & 1023;
      float val = acc[ct][r] + bv_;
      if (z == 0) val *= 0.125f;  // fold score scaling into q
      size_t addr = (z < 2)
          ? ((((size_t)n * HH + hh) * TT + t) * DHD + dh)     // q,k: [N,H,T,64]
          : ((((size_t)n * HH + hh) * DHD + dh) * TT + t);    // v : [N,H,64,T]
      out[addr] = f2bf(val);
    }
  }
}

// ---------------- output projection GEMM ----------------
__global__ __launch_bounds__(256) void kt_outproj(
    const short* __restrict__ A, const short* __restrict__ WT,
    const float* __restrict__ bias, float* __restrict__ out)
{
  __shared__ alignas(16) short As[64][40];
  __shared__ alignas(16) short Bs[64][40];
  int tid = threadIdx.x;
  int w = tid >> 6, lane = tid & 63, g = lane >> 4, c16 = lane & 15;
  int m0 = blockIdx.x * 64, c0 = blockIdx.y * 64;
  int srow = tid >> 2, skg = (tid & 3) * 8;
  f32x4 acc[4] = {};

  for (int kk = 0; kk < DD; kk += 32) {
    *(bf16x8*)&As[srow][skg] = *(const bf16x8*)(A + (size_t)(m0 + srow) * DD + kk + skg);
    *(bf16x8*)&Bs[srow][skg] = *(const bf16x8*)(WT + (size_t)(c0 + srow) * DD + kk + skg);
    __syncthreads();
    bf16x8 af = *(const bf16x8*)&As[w * 16 + c16][g * 8];
#pragma unroll
    for (int ct = 0; ct < 4; ++ct) {
      bf16x8 bfv = *(const bf16x8*)&Bs[ct * 16 + c16][g * 8];
      acc[ct] = MFMA(af, bfv, acc[ct]);
    }
    __syncthreads();
  }

#pragma unroll
  for (int ct = 0; ct < 4; ++ct) {
    int c = c0 + ct * 16 + c16;
    float bv_ = bias[c];
#pragma unroll
    for (int r = 0; r < 4; ++r) {
      int m = m0 + w * 16 + g * 4 + r;
      out[(size_t)m * DD + c] = acc[ct][r] + bv_;
    }
  }
}

// ---------------- fused attention, v2 ----------------
// 512 threads = 8 waves; block = (n, qt) -> 16 q-rows. Wave w owns k-slice
// [w*128, w*128+128) for QK^T/softmax. mask/segms hoisted to registers
// (h-invariant). Single-barrier softmax via per-wave (m_w, S_w) exchange.
// PV: each wave computes a full-k 16x16 output tile (wave pairs redundant),
// stores directly -> 2 barriers per head.
__global__ __launch_bounds__(512, 4) void kt_attn(
    const short* __restrict__ qbuf, const short* __restrict__ kbuf, const short* __restrict__ vT,
    const float* __restrict__ segms, const int* __restrict__ mask,
    short* __restrict__ attn, float* __restrict__ pmean)
{
  int bx = blockIdx.x;
  int n = bx & 7, qt = bx >> 3;          // XCD-friendly: XCD x sees one batch n
  int tid = threadIdx.x, w = tid >> 6, lane = tid & 63, g = lane >> 4, c16 = lane & 15;
  int kw = w * 128;

  __shared__ alignas(16) short pbuf[16][1032];  // full 16 x 1024 probs (bf16), pad->2-way banks
  __shared__ float red_m[8][16];
  __shared__ float red_s[8][16];

  // ---- hoist mask bits + segms (h-invariant) ----
  unsigned mm = 0u;
  float segs[4][8];
  float pm[4][8];
#pragma unroll
  for (int r = 0; r < 4; ++r) {
    size_t base = ((size_t)(n * TT) + qt * 16 + g * 4 + r) * TT + kw + c16;
#pragma unroll
    for (int ct = 0; ct < 8; ++ct) {
      if (mask[base + ct * 16]) mm |= 1u << (r * 8 + ct);
      segs[r][ct] = segms[base + ct * 16];
      pm[r][ct] = 0.f;
    }
  }

  for (int h = 0; h < HH; ++h) {
    const short* qp = qbuf + ((((size_t)n * HH + h) * TT) + qt * 16) * DHD;
    const short* kp = kbuf + (((size_t)n * HH + h) * TT) * DHD;
    const short* vp = vT   + (((size_t)n * HH + h) * DHD) * TT;

    bf16x8 aq0 = *(const bf16x8*)(qp + c16 * DHD + g * 8);
    bf16x8 aq1 = *(const bf16x8*)(qp + c16 * DHD + g * 8 + 32);

    // ---- QK^T over this wave's 128-k slice (q pre-scaled by 1/8) ----
    f32x4 sc[8];
    __builtin_amdgcn_s_setprio(1);
#pragma unroll
    for (int ct = 0; ct < 8; ++ct) {
      const short* kpp = kp + (size_t)(kw + ct * 16 + c16) * DHD + g * 8;
      f32x4 a = {};
      a = MFMA(aq0, *(const bf16x8*)kpp, a);
      a = MFMA(aq1, *(const bf16x8*)(kpp + 32), a);
      sc[ct] = a;
    }
    __builtin_amdgcn_s_setprio(0);

    // ---- mask + wave-local row max ----
    float mx[4] = {-3e38f, -3e38f, -3e38f, -3e38f};
#pragma unroll
    for (int r = 0; r < 4; ++r)
#pragma unroll
      for (int ct = 0; ct < 8; ++ct) {
        float s = ((mm >> (r * 8 + ct)) & 1u) ? sc[ct][r] : -1e9f;
        sc[ct][r] = s;
        mx[r] = fmaxf(mx[r], s);
      }
#pragma unroll
    for (int r = 0; r < 4; ++r) {
      mx[r] = fmaxf(mx[r], __shfl_xor(mx[r], 1, 16));
      mx[r] = fmaxf(mx[r], __shfl_xor(mx[r], 2, 16));
      mx[r] = fmaxf(mx[r], __shfl_xor(mx[r], 4, 16));
      mx[r] = fmaxf(mx[r], __shfl_xor(mx[r], 8, 16));
    }

    // ---- exp with LOCAL max (p<=1 safe) + wave-local sum ----
    float sm[4] = {0.f, 0.f, 0.f, 0.f};
#pragma unroll
    for (int ct = 0; ct < 8; ++ct)
#pragma unroll
      for (int r = 0; r < 4; ++r) {
        float p = __expf(sc[ct][r] - mx[r]);
        sc[ct][r] = p;
        sm[r] += p;
      }
#pragma unroll
    for (int r = 0; r < 4; ++r) {
      sm[r] += __shfl_xor(sm[r], 1, 16);
      sm[r] += __shfl_xor(sm[r], 2, 16);
      sm[r] += __shfl_xor(sm[r], 4, 16);
      sm[r] += __shfl_xor(sm[r], 8, 16);
    }
    if (c16 == 0) {
#pragma unroll
      for (int r = 0; r < 4; ++r) {
        red_m[w][g * 4 + r] = mx[r];
        red_s[w][g * 4 + r] = sm[r];
      }
    }
    __syncthreads();  // barrier A: (m,S) ready; also protects pbuf from prev PV reads

    // ---- combine: scale_w = exp(m_w - m*) / Z ----
    float scl[4];
#pragma unroll
    for (int r = 0; r < 4; ++r) {
      int q = g * 4 + r;
      float m0 = red_m[0][q], m1 = red_m[1][q], m2 = red_m[2][q], m3 = red_m[3][q];
      float m4 = red_m[4][q], m5 = red_m[5][q], m6 = red_m[6][q], m7 = red_m[7][q];
      float ms = fmaxf(fmaxf(fmaxf(m0, m1), fmaxf(m2, m3)),
                       fmaxf(fmaxf(m4, m5), fmaxf(m6, m7)));
      float Z = red_s[0][q] * __expf(m0 - ms) + red_s[1][q] * __expf(m1 - ms)
              + red_s[2][q] * __expf(m2 - ms) + red_s[3][q] * __expf(m3 - ms)
              + red_s[4][q] * __expf(m4 - ms) + red_s[5][q] * __expf(m5 - ms)
              + red_s[6][q] * __expf(m6 - ms) + red_s[7][q] * __expf(m7 - ms);
      scl[r] = __expf(mx[r] - ms) / Z;
    }

    // ---- probs = p*scale*segms ; accumulate pmean ; stash bf16 ----
#pragma unroll
    for (int r = 0; r < 4; ++r)
#pragma unroll
      for (int ct = 0; ct < 8; ++ct) {
        float pr = sc[ct][r] * scl[r] * segs[r][ct];
        pm[r][ct] += pr;
        pbuf[g * 4 + r][kw + ct * 16 + c16] = f2bf(pr);
      }
    __syncthreads();  // barrier B: pbuf ready

    // ---- PV: full k, 16 output cols per wave (pairs w / w+4 redundant) ----
    int cg = (w & 3) * 16;
    const short* vpp = vp + (size_t)(cg + c16) * TT + g * 8;
    f32x4 oa[4] = {};
    __builtin_amdgcn_s_setprio(1);
#pragma unroll
    for (int ks = 0; ks < 32; ++ks) {
      bf16x8 pa = *(const bf16x8*)&pbuf[c16][ks * 32 + g * 8];
      bf16x8 bv = *(const bf16x8*)(vpp + ks * 32);
      oa[ks & 3] = MFMA(pa, bv, oa[ks & 3]);
    }
    __builtin_amdgcn_s_setprio(0);

    if (w < 4) {
      short* ap = attn + ((size_t)(n * TT) + qt * 16 + g * 4) * DD + h * DHD + cg + c16;
#pragma unroll
      for (int r = 0; r < 4; ++r) {
        float v0 = oa[0][r] + oa[1][r] + oa[2][r] + oa[3][r];
        ap[(size_t)r * DD] = f2bf(v0);
      }
    }
  }

  // ---- write probs mean (1/H) ----
#pragma unroll
  for (int r = 0; r < 4; ++r) {
    size_t base = ((size_t)(n * TT) + qt * 16 + g * 4 + r) * TT + kw + c16;
#pragma unroll
    for (int ct = 0; ct < 8; ++ct)
      pmean[base + ct * 16] = pm[r][ct] * 0.125f;
  }
}

extern "C" void kernel_launch(void* const* d_in, const int* in_sizes, int n_in,
                              void* d_out, int out_size, void* d_ws, size_t ws_size,
                              hipStream_t stream) {
  const float* query = (const float*)d_in[0];
  const float* key_  = (const float*)d_in[1];
  const float* value = (const float*)d_in[2];
  const float* segms = (const float*)d_in[3];
  const int*   mask  = (const int*)d_in[4];
  const float* Wq = (const float*)d_in[5];
  const float* bq = (const float*)d_in[6];
  const float* Wk = (const float*)d_in[7];
  const float* bk = (const float*)d_in[8];
  const float* Wv = (const float*)d_in[9];
  const float* bv = (const float*)d_in[10];
  const float* Wo = (const float*)d_in[11];
  const float* bo = (const float*)d_in[12];

  char* ws = (char*)d_ws;
  short* WT   = (short*)(ws);                        // 4 x 512x512 bf16 = 2 MB
  short* qb   = (short*)(ws + ((size_t)2  << 20));   // [N,H,T,64] bf16 = 8 MB
  short* kb   = (short*)(ws + ((size_t)10 << 20));   // [N,H,T,64] bf16 = 8 MB
  short* vT   = (short*)(ws + ((size_t)18 << 20));   // [N,H,64,T] bf16 = 8 MB
  short* attn = (short*)(ws + ((size_t)26 << 20));   // [N,T,D]   bf16 = 8 MB
  float* outp  = (float*)d_out;
  float* pmean = outp + (size_t)NB * TT * DD;

  kt_transpose<<<dim3(16, 16, 4), dim3(32, 8), 0, stream>>>(Wq, Wk, Wv, Wo, WT);
  kt_proj<<<dim3(128, 8, 3), 256, 0, stream>>>(query, key_, value, WT, bq, bk, bv, qb, kb, vT);
  kt_attn<<<dim3(512), dim3(512), 0, stream>>>(qb, kb, vT, segms, mask, attn, pmean);
  kt_outproj<<<dim3(128, 8), 256, 0, stream>>>(attn, WT + (size_t)3 * DD * DD, bo, outp);
}

// Round 2
// 241.509 us; speedup vs baseline: 1.3663x; 1.3663x over previous
//
#include <hip/hip_runtime.h>
#include <hip/hip_bf16.h>
#include <hip/hip_fp16.h>
#include <cstdint>
#include <cstddef>

#define NB 8
#define TT 1024
#define DD 512
#define HH 8
#define DHD 64

using bf16x8 = __attribute__((ext_vector_type(8))) short;
using f32x4  = __attribute__((ext_vector_type(4))) float;

#define MFMA(a, b, c) __builtin_amdgcn_mfma_f32_16x16x32_bf16((a), (b), (c), 0, 0, 0)

__device__ __forceinline__ short f2bf(float f) {
  union { float f; uint32_t u; } x; x.f = f;
  uint32_t r = x.u + 0x7fffu + ((x.u >> 16) & 1u);
  return (short)(r >> 16);
}

// ---------------- weight transpose + f32->bf16 ----------------
__global__ __launch_bounds__(256) void kt_transpose(
    const float* __restrict__ W0, const float* __restrict__ W1,
    const float* __restrict__ W2, const float* __restrict__ W3,
    short* __restrict__ WT)
{
  __shared__ float tile[32][33];
  int z = blockIdx.z;
  const float* W = (z == 0) ? W0 : (z == 1) ? W1 : (z == 2) ? W2 : W3;
  short* out = WT + (size_t)z * DD * DD;
  int tx = threadIdx.x, ty = threadIdx.y;  // (32, 8)
  int bx = blockIdx.x * 32, by = blockIdx.y * 32;
#pragma unroll
  for (int kq = 0; kq < 4; ++kq)
    tile[ty + kq * 8][tx] = W[(size_t)(by + ty + kq * 8) * DD + bx + tx];
  __syncthreads();
#pragma unroll
  for (int kq = 0; kq < 4; ++kq)
    out[(size_t)(bx + ty + kq * 8) * DD + by + tx] = f2bf(tile[tx][ty + kq * 8]);
}

// ---------------- QKV projection GEMM ----------------
// z: 0=Q (scaled by 1/8, layout [N,H,T,64]), 1=K ([N,H,T,64]), 2=V ([N,H,64,T])
__global__ __launch_bounds__(256) void kt_proj(
    const float* __restrict__ Xq, const float* __restrict__ Xk, const float* __restrict__ Xv,
    const short* __restrict__ WTall,
    const float* __restrict__ bq, const float* __restrict__ bk, const float* __restrict__ bv,
    short* __restrict__ qb, short* __restrict__ kb, short* __restrict__ vT)
{
  int z = blockIdx.z;
  const float* X    = (z == 0) ? Xq : (z == 1) ? Xk : Xv;
  const short* WT   = WTall + (size_t)z * DD * DD;
  const float* bias = (z == 0) ? bq : (z == 1) ? bk : bv;
  short* out        = (z == 0) ? qb : (z == 1) ? kb : vT;

  __shared__ alignas(16) short As[64][40];
  __shared__ alignas(16) short Bs[64][40];
  int tid = threadIdx.x;
  int w = tid >> 6, lane = tid & 63, g = lane >> 4, c16 = lane & 15;
  int m0 = blockIdx.x * 64, c0 = blockIdx.y * 64;
  int srow = tid >> 2, skg = (tid & 3) * 8;
  f32x4 acc[4] = {};

  for (int kk = 0; kk < DD; kk += 32) {
    const float* ap = X + (size_t)(m0 + srow) * DD + kk + skg;
    float4 a0 = *(const float4*)ap;
    float4 a1 = *(const float4*)(ap + 4);
    bf16x8 av;
    av[0] = f2bf(a0.x); av[1] = f2bf(a0.y); av[2] = f2bf(a0.z); av[3] = f2bf(a0.w);
    av[4] = f2bf(a1.x); av[5] = f2bf(a1.y); av[6] = f2bf(a1.z); av[7] = f2bf(a1.w);
    *(bf16x8*)&As[srow][skg] = av;
    *(bf16x8*)&Bs[srow][skg] = *(const bf16x8*)(WT + (size_t)(c0 + srow) * DD + kk + skg);
    __syncthreads();
    bf16x8 af = *(const bf16x8*)&As[w * 16 + c16][g * 8];
#pragma unroll
    for (int ct = 0; ct < 4; ++ct) {
      bf16x8 bfv = *(const bf16x8*)&Bs[ct * 16 + c16][g * 8];
      acc[ct] = MFMA(af, bfv, acc[ct]);
    }
    __syncthreads();
  }

#pragma unroll
  for (int ct = 0; ct < 4; ++ct) {
    int c = c0 + ct * 16 + c16;
    float bv_ = bias[c];
    int hh = c >> 6, dh = c & 63;
#pragma unroll
    for (int r = 0; r < 4; ++r) {
      int m = m0 + w * 16 + g * 4 + r;
      int n = m >> 10, t = m & 1023;
      float val = acc[ct][r] + bv_;
      if (z == 0) val *= 0.125f;  // fold score scaling into q
      size_t addr = (z < 2)
          ? ((((size_t)n * HH + hh) * TT + t) * DHD + dh)     // q,k: [N,H,T,64]
          : ((((size_t)n * HH + hh) * DHD + dh) * TT + t);    // v : [N,H,64,T]
      out[addr] = f2bf(val);
    }
  }
}

// ---------------- output projection GEMM ----------------
__global__ __launch_bounds__(256) void kt_outproj(
    const short* __restrict__ A, const short* __restrict__ WT,
    const float* __restrict__ bias, float* __restrict__ out)
{
  __shared__ alignas(16) short As[64][40];
  __shared__ alignas(16) short Bs[64][40];
  int tid = threadIdx.x;
  int w = tid >> 6, lane = tid & 63, g = lane >> 4, c16 = lane & 15;
  int m0 = blockIdx.x * 64, c0 = blockIdx.y * 64;
  int srow = tid >> 2, skg = (tid & 3) * 8;
  f32x4 acc[4] = {};

  for (int kk = 0; kk < DD; kk += 32) {
    *(bf16x8*)&As[srow][skg] = *(const bf16x8*)(A + (size_t)(m0 + srow) * DD + kk + skg);
    *(bf16x8*)&Bs[srow][skg] = *(const bf16x8*)(WT + (size_t)(c0 + srow) * DD + kk + skg);
    __syncthreads();
    bf16x8 af = *(const bf16x8*)&As[w * 16 + c16][g * 8];
#pragma unroll
    for (int ct = 0; ct < 4; ++ct) {
      bf16x8 bfv = *(const bf16x8*)&Bs[ct * 16 + c16][g * 8];
      acc[ct] = MFMA(af, bfv, acc[ct]);
    }
    __syncthreads();
  }

#pragma unroll
  for (int ct = 0; ct < 4; ++ct) {
    int c = c0 + ct * 16 + c16;
    float bv_ = bias[c];
#pragma unroll
    for (int r = 0; r < 4; ++r) {
      int m = m0 + w * 16 + g * 4 + r;
      out[(size_t)m * DD + c] = acc[ct][r] + bv_;
    }
  }
}

// ---------------- fused attention, v3 ----------------
// 512 threads = 8 waves; block = (n, qt) -> 16 q-rows; wave w owns k-slice
// [w*128, w*128+128) for BOTH QK^T/softmax AND PV (no redundancy).
// mask bits (1 VGPR) + segms (fp16-packed, 16 VGPRs) hoisted; pm f32 (32 VGPRs).
// Single-barrier softmax (local-max exp + (m,S) exchange). Per-wave pbuf
// (no barrier). Cross-wave PV reduce via outred + 1 barrier. 2 barriers/head.
__global__ __launch_bounds__(512, 2) void kt_attn(
    const short* __restrict__ qbuf, const short* __restrict__ kbuf, const short* __restrict__ vT,
    const float* __restrict__ segms, const int* __restrict__ mask,
    short* __restrict__ attn, float* __restrict__ pmean)
{
  int bx = blockIdx.x;
  int n = bx & 7, qt = bx >> 3;          // XCD-local batch: all blocks of n on XCD n
  int tid = threadIdx.x, w = tid >> 6, lane = tid & 63, g = lane >> 4, c16 = lane & 15;
  int kw = w * 128;

  __shared__ alignas(16) short pbuf[8][16][136];   // per-wave probs slice, 16B-aligned rows
  __shared__ alignas(16) float outred[8][16][66];  // per-wave PV partials
  __shared__ alignas(16) float red_m[8][16];
  __shared__ alignas(16) float red_s[8][16];

  // ---- hoist mask bits + segms (fp16 packed); h-invariant ----
  unsigned mm = 0u;
  uint32_t sgp[4][4];
  uint32_t rbase[4];
  float pm[4][8];
#pragma unroll
  for (int r = 0; r < 4; ++r) {
    uint32_t base = ((uint32_t)(n * TT) + qt * 16 + g * 4 + r) * TT + kw + c16;
    rbase[r] = base;
#pragma unroll
    for (int ct = 0; ct < 8; ct += 2) {
      if (mask[base + ct * 16])      mm |= 1u << (r * 8 + ct);
      if (mask[base + ct * 16 + 16]) mm |= 1u << (r * 8 + ct + 1);
      float s0 = segms[base + ct * 16], s1 = segms[base + ct * 16 + 16];
      sgp[r][ct >> 1] = (uint32_t)__half_as_ushort(__float2half(s0))
                      | ((uint32_t)__half_as_ushort(__float2half(s1)) << 16);
      pm[r][ct] = 0.f; pm[r][ct + 1] = 0.f;
    }
  }

  for (int h = 0; h < HH; ++h) {
    const short* qp = qbuf + ((((size_t)n * HH + h) * TT) + qt * 16) * DHD;
    const short* kp = kbuf + (((size_t)n * HH + h) * TT) * DHD;
    const short* vp = vT   + (((size_t)n * HH + h) * DHD) * TT;

    bf16x8 aq0 = *(const bf16x8*)(qp + c16 * DHD + g * 8);
    bf16x8 aq1 = *(const bf16x8*)(qp + c16 * DHD + g * 8 + 32);

    // ---- QK^T over this wave's 128-k slice (q pre-scaled by 1/8) ----
    f32x4 sc[8];
    __builtin_amdgcn_s_setprio(1);
#pragma unroll
    for (int ct = 0; ct < 8; ++ct) {
      const short* kpp = kp + (size_t)(kw + ct * 16 + c16) * DHD + g * 8;
      f32x4 a = {};
      a = MFMA(aq0, *(const bf16x8*)kpp, a);
      a = MFMA(aq1, *(const bf16x8*)(kpp + 32), a);
      sc[ct] = a;
    }
    __builtin_amdgcn_s_setprio(0);

    // ---- mask + wave-local row max ----
    float mx[4] = {-3e38f, -3e38f, -3e38f, -3e38f};
#pragma unroll
    for (int r = 0; r < 4; ++r)
#pragma unroll
      for (int ct = 0; ct < 8; ++ct) {
        float s = ((mm >> (r * 8 + ct)) & 1u) ? sc[ct][r] : -1e9f;
        sc[ct][r] = s;
        mx[r] = fmaxf(mx[r], s);
      }
#pragma unroll
    for (int r = 0; r < 4; ++r) {
      mx[r] = fmaxf(mx[r], __shfl_xor(mx[r], 1, 16));
      mx[r] = fmaxf(mx[r], __shfl_xor(mx[r], 2, 16));
      mx[r] = fmaxf(mx[r], __shfl_xor(mx[r], 4, 16));
      mx[r] = fmaxf(mx[r], __shfl_xor(mx[r], 8, 16));
    }

    // ---- exp with LOCAL max (p<=1 safe) + wave-local sum ----
    float sm[4] = {0.f, 0.f, 0.f, 0.f};
#pragma unroll
    for (int ct = 0; ct < 8; ++ct)
#pragma unroll
      for (int r = 0; r < 4; ++r) {
        float p = __expf(sc[ct][r] - mx[r]);
        sc[ct][r] = p;
        sm[r] += p;
      }
#pragma unroll
    for (int r = 0; r < 4; ++r) {
      sm[r] += __shfl_xor(sm[r], 1, 16);
      sm[r] += __shfl_xor(sm[r], 2, 16);
      sm[r] += __shfl_xor(sm[r], 4, 16);
      sm[r] += __shfl_xor(sm[r], 8, 16);
    }
    if (c16 == 0) {
#pragma unroll
      for (int r = 0; r < 4; ++r) {
        red_m[w][g * 4 + r] = mx[r];
        red_s[w][g * 4 + r] = sm[r];
      }
    }
    __syncthreads();  // barrier A: (m,S) ready; also fences outred/red reuse

    // ---- combine: scale_w = exp(m_w - m*) / Z  (vectorized LDS reads) ----
    float msx[4] = {-3e38f, -3e38f, -3e38f, -3e38f};
#pragma unroll
    for (int wi = 0; wi < 8; ++wi) {
      f32x4 v = *(const f32x4*)&red_m[wi][g * 4];
#pragma unroll
      for (int r = 0; r < 4; ++r) msx[r] = fmaxf(msx[r], v[r]);
    }
    float Z[4] = {0.f, 0.f, 0.f, 0.f};
#pragma unroll
    for (int wi = 0; wi < 8; ++wi) {
      f32x4 vm = *(const f32x4*)&red_m[wi][g * 4];
      f32x4 vs = *(const f32x4*)&red_s[wi][g * 4];
#pragma unroll
      for (int r = 0; r < 4; ++r) Z[r] += vs[r] * __expf(vm[r] - msx[r]);
    }
    float scl[4];
#pragma unroll
    for (int r = 0; r < 4; ++r) scl[r] = __expf(mx[r] - msx[r]) / Z[r];

    // ---- probs = p*scale*segms ; accumulate pmean ; stash bf16 (own slice) ----
#pragma unroll
    for (int r = 0; r < 4; ++r)
#pragma unroll
      for (int ct = 0; ct < 8; ++ct) {
        float seg = __half2float(__ushort_as_half(
            (unsigned short)(sgp[r][ct >> 1] >> ((ct & 1) * 16))));
        float pr = sc[ct][r] * scl[r] * seg;
        pm[r][ct] += pr;
        pbuf[w][g * 4 + r][ct * 16 + c16] = f2bf(pr);
      }
    // no barrier: pbuf slice is wave-private (compiler inserts lgkmcnt wait)

    // ---- PV over this wave's 128-k slice ----
    f32x4 oa[4] = {};
    __builtin_amdgcn_s_setprio(1);
#pragma unroll
    for (int ks = 0; ks < 4; ++ks) {
      bf16x8 pa = *(const bf16x8*)&pbuf[w][c16][ks * 32 + g * 8];
#pragma unroll
      for (int ct = 0; ct < 4; ++ct) {
        const short* vpp = vp + (size_t)(ct * 16 + c16) * TT + kw + ks * 32 + g * 8;
        oa[ct] = MFMA(pa, *(const bf16x8*)vpp, oa[ct]);
      }
    }
    __builtin_amdgcn_s_setprio(0);

#pragma unroll
    for (int ct = 0; ct < 4; ++ct)
#pragma unroll
      for (int r = 0; r < 4; ++r)
        outred[w][g * 4 + r][ct * 16 + c16] = oa[ct][r];
    __syncthreads();  // barrier C: outred ready

    // ---- cross-wave reduce (8 partials) + write attn[n][t][h*64+d] ----
    {
      int q = tid >> 5, dg = (tid & 31) * 2;
      float v0 = 0.f, v1 = 0.f;
#pragma unroll
      for (int wi = 0; wi < 8; ++wi) {
        v0 += outred[wi][q][dg];
        v1 += outred[wi][q][dg + 1];
      }
      ushort2 st;
      st.x = (unsigned short)f2bf(v0);
      st.y = (unsigned short)f2bf(v1);
      *(ushort2*)(attn + ((size_t)(n * TT) + qt * 16 + q) * DD + h * DHD + dg) = st;
    }
    // next head's red/outred writes are fenced by barrier A of that head
  }

  // ---- write probs mean (1/H) ----
#pragma unroll
  for (int r = 0; r < 4; ++r)
#pragma unroll
    for (int ct = 0; ct < 8; ++ct)
      pmean[rbase[r] + ct * 16] = pm[r][ct] * 0.125f;
}

extern "C" void kernel_launch(void* const* d_in, const int* in_sizes, int n_in,
                              void* d_out, int out_size, void* d_ws, size_t ws_size,
                              hipStream_t stream) {
  const float* query = (const float*)d_in[0];
  const float* key_  = (const float*)d_in[1];
  const float* value = (const float*)d_in[2];
  const float* segms = (const float*)d_in[3];
  const int*   mask  = (const int*)d_in[4];
  const float* Wq = (const float*)d_in[5];
  const float* bq = (const float*)d_in[6];
  const float* Wk = (const float*)d_in[7];
  const float* bk = (const float*)d_in[8];
  const float* Wv = (const float*)d_in[9];
  const float* bv = (const float*)d_in[10];
  const float* Wo = (const float*)d_in[11];
  const float* bo = (const float*)d_in[12];

  char* ws = (char*)d_ws;
  short* WT   = (short*)(ws);                        // 4 x 512x512 bf16 = 2 MB
  short* qb   = (short*)(ws + ((size_t)2  << 20));   // [N,H,T,64] bf16 = 8 MB
  short* kb   = (short*)(ws + ((size_t)10 << 20));   // [N,H,T,64] bf16 = 8 MB
  short* vT   = (short*)(ws + ((size_t)18 << 20));   // [N,H,64,T] bf16 = 8 MB
  short* attn = (short*)(ws + ((size_t)26 << 20));   // [N,T,D]   bf16 = 8 MB
  float* outp  = (float*)d_out;
  float* pmean = outp + (size_t)NB * TT * DD;

  kt_transpose<<<dim3(16, 16, 4), dim3(32, 8), 0, stream>>>(Wq, Wk, Wv, Wo, WT);
  kt_proj<<<dim3(128, 8, 3), 256, 0, stream>>>(query, key_, value, WT, bq, bk, bv, qb, kb, vT);
  kt_attn<<<dim3(512), dim3(512), 0, stream>>>(qb, kb, vT, segms, mask, attn, pmean);
  kt_outproj<<<dim3(128, 8), 256, 0, stream>>>(attn, WT + (size_t)3 * DD * DD, bo, outp);
}